// Round 19
// baseline (208.332 us; speedup 1.0000x reference)
//
#include <hip/hip_runtime.h>
#include <hip/hip_cooperative_groups.h>
#include <stdint.h>

namespace cg = cooperative_groups;

typedef unsigned int u32;
typedef unsigned long long u64;
typedef unsigned short us;
using short8 = __attribute__((ext_vector_type(8))) short;
using us8    = __attribute__((ext_vector_type(8))) us;
using f32x4  = __attribute__((ext_vector_type(4))) float;

#define BT 16
#define NPT 1024

struct Params {
    const float *xyz, *pts;
    const float *w1a, *b1a, *w1b, *b1b, *w1c, *b1c;
    const float *w2a, *b2a, *w2b, *b2b, *w2c, *b2c;
    u64* keys;
    us *wf1a, *wf1b, *wf1c, *wf2a, *wf2b, *wf2c, *ptsbf, *newbf;
    float* outp;
};

// ---------- bf16 helpers ----------
__device__ __forceinline__ us f2bf(float f) {           // RNE f32 -> bf16
    u32 u = __float_as_uint(f);
    u += 0x7fffu + ((u >> 16) & 1u);
    return (us)(u >> 16);
}
__device__ __forceinline__ float bf2f(us v) { return __uint_as_float(((u32)v) << 16); }
__device__ __forceinline__ u32 packbf(float lo, float hi) {  // validated software pack
    return (u32)f2bf(lo) | ((u32)f2bf(hi) << 16);            // (cvt_pk asm corrupted: r8)
}

// ---------- weight prep: conv-a layout (octet-contiguous, neighbor-split K) ----------
__device__ void wprep_a(int tid, const float* __restrict__ w, us* __restrict__ dst,
                        int Cfeat, int Creal, int NOCT) {
    int lane = tid & 63, ct = (tid >> 6) & 7, kt = tid >> 9;
    int o = ct * 16 + (lane & 15);
    int h = lane >> 4;
    int ci = kt * 4 + h;
    int p = (ci >= NOCT) ? 1 : 0;
    int q = ci - p * NOCT;
    us8 v;
#pragma unroll
    for (int j = 0; j < 8; ++j) {
        int c = q * 8 + j;
        int ref = (c < Cfeat) ? c + 3 : ((c < Cfeat + 3) ? c - Cfeat : -1);
        v[j] = (ref >= 0) ? f2bf(w[((size_t)o * Creal + ref) * 2 + p]) : (us)0;
    }
    *(us8*)(dst + (size_t)tid * 8) = v;
}

// ---------- weight prep: conv-b/c layout (pair-interleaved K, matches epilogue) ----------
__device__ void wprep_b(int tid, const float* __restrict__ w, us* __restrict__ dst) {
    int lane = tid & 63, ct = (tid >> 6) & 7, kt = tid >> 9;
    int o = ct * 16 + (lane & 15);
    int k0 = kt * 32 + ((lane >> 4) << 3);
    us8 v;
#pragma unroll
    for (int j = 0; j < 8; ++j) v[j] = f2bf(w[(size_t)o * 256 + k0 + j]);
    *(us8*)(dst + (size_t)tid * 8) = v;
}

// ---------- prep unit (268): weights | xyz copy | ptsbf rows | newbf xyz/pad ----------
__device__ void prep_unit(int u2, const Params& p) {
    const int t = threadIdx.x;
    if (u2 < 92) {
        if (u2 < 10)      wprep_a(u2 * 256 + t, p.w1a, p.wf1a, 64, 67, 10);
        else if (u2 < 26) wprep_b((u2 - 10) * 256 + t, p.w1b, p.wf1b);
        else if (u2 < 42) wprep_b((u2 - 26) * 256 + t, p.w1c, p.wf1c);
        else if (u2 < 60) wprep_a((u2 - 42) * 256 + t, p.w2a, p.wf2a, 128, 131, 18);
        else if (u2 < 76) wprep_b((u2 - 60) * 256 + t, p.w2b, p.wf2b);
        else              wprep_b((u2 - 76) * 256 + t, p.w2c, p.wf2c);
    } else if (u2 < 140) {
        int id = (u2 - 92) * 256 + t;
        ((float4*)p.outp)[id] = ((const float4*)p.xyz)[id];
    } else if (u2 < 204) {
        int r = (u2 - 140) * 256 + t;
        const float4* pr = (const float4*)(p.pts + ((size_t)r << 6));
        u32* dst = (u32*)(p.ptsbf + (size_t)r * 80);
#pragma unroll
        for (int i = 0; i < 16; ++i) {
            float4 f = pr[i];
            dst[2 * i]     = packbf(f.x, f.y);
            dst[2 * i + 1] = packbf(f.z, f.w);
        }
        const float* xr = p.xyz + (size_t)r * 3;
        dst[32] = packbf(xr[0], xr[1]);
        dst[33] = packbf(xr[2], 0.f);
#pragma unroll
        for (int i = 34; i < 40; ++i) dst[i] = 0u;
    } else {
        int r = (u2 - 204) * 256 + t;
        u32* dst = (u32*)(p.newbf + (size_t)r * 144);
        const float* xr = p.xyz + (size_t)r * 3;
        dst[64] = packbf(xr[0], xr[1]);
        dst[65] = packbf(xr[2], 0.f);
#pragma unroll
        for (int i = 66; i < 72; ++i) dst[i] = 0u;
    }
}

// ---------- stage-1 unit: register-resident select + conv chain (r17-verbatim) ----------
__device__ void s1_unit(int uraw, const Params& p, char* smem, u64 (*kfin)[8],
                        float* snn) {
    constexpr int KTA = 5, NOCT = 10, RSTR = 80, FIXC = 64, FIXQ = 8;
    us* abuf = (us*)smem;
    us* cbuf = (us*)(smem + 16384);

    const int u = (int)((((u32)uraw & 7u) << 7) | ((u32)uraw >> 3));  // T1 swizzle
    const int t = threadIdx.x, wid = t >> 6, lane = t & 63;
    const int li = lane & 15, h = lane >> 4;
    const int g0 = u * 16;               // global group base
    const int b = u >> 6;
    const int nb0 = g0 & (NPT - 1);      // batch-local base (16-aligned)
    const float* xg = p.xyz + (size_t)b * 3072;
    const us* fb = p.ptsbf + (size_t)b * NPT * RSTR;

    // ---- one-time: this lane's 4 j-points into registers ----
    const int j0 = (wid << 8) + (lane << 2);
    float4 c0 = *(const float4*)(xg + (size_t)j0 * 3);
    float4 c1 = *(const float4*)(xg + (size_t)j0 * 3 + 4);
    float4 c2 = *(const float4*)(xg + (size_t)j0 * 3 + 8);
    const float jxc[4] = {c0.x, c0.w, c1.z, c2.y};
    const float jyc[4] = {c0.y, c1.x, c1.w, c2.z};
    const float jzc[4] = {c0.z, c1.y, c2.x, c2.w};

    __syncthreads();                     // LDS reuse guard (multi-unit stride)
    if (t < 48) snn[t] = xg[(size_t)nb0 * 3 + t];
    if (t < 128)
        kfin[t >> 3][t & 7] = ((u64)__float_as_uint(0.04f) << 32) | (u32)(nb0 + (t >> 3));
    __syncthreads();

    // ---- select sweep: 16 n x 4 register-j per lane ----
    for (int i = 0; i < 16; ++i) {
        const float xn = snn[i * 3], yn = snn[i * 3 + 1], zn = snn[i * 3 + 2];
#pragma unroll
        for (int jj = 0; jj < 4; ++jj) {
            float dx = __fadd_rn(jxc[jj], -xn);
            float dy = __fadd_rn(jyc[jj], -yn);
            float dz = __fadd_rn(jzc[jj], -zn);
            // exact IEEE f32, no contraction: must match numpy bit-for-bit
            float d = __fadd_rn(__fadd_rn(__fmul_rn(dx, dx), __fmul_rn(dy, dy)),
                                __fmul_rn(dz, dz));
            if (d > 1e-10f && d < 0.04f) {
                int oct = ((int)__fadd_rn(dx, 1.0f)) * 4 + ((int)__fadd_rn(dy, 1.0f)) * 2 +
                          ((int)__fadd_rn(dz, 1.0f));
                u64 key = ((u64)__float_as_uint(d) << 32) | (u32)(j0 + jj);
                atomicMin(&kfin[i][oct], key);
            }
        }
    }
    __syncthreads();

    // ---- publish keys for stage 2 + extract this thread's J's ----
    if (t < 128)
        p.keys[(((size_t)g0 + (t >> 3)) << 3) + (t & 7)] = kfin[t >> 3][t & 7];
    const int n_loc_c = wid * 4 + (li >> 2), pos = li & 3;
    const int J0 = (int)(u32)kfin[n_loc_c][2 * pos];
    const int J1 = (int)(u32)kfin[n_loc_c][2 * pos + 1];
    const int N = nb0 + n_loc_c;
    __syncthreads();

    const us* row0 = fb + (size_t)J0 * RSTR;
    const us* row1 = fb + (size_t)J1 * RSTR;
    us8 xn8 = *(const us8*)(fb + (size_t)N * RSTR + FIXC);
    const float xn0 = bf2f(xn8[0]), xn1 = bf2f(xn8[1]), xn2 = bf2f(xn8[2]);

    // ---- conv-a ----
    f32x4 acc[8];
#pragma unroll
    for (int ct = 0; ct < 8; ++ct) {
        float bv = p.b1a[ct * 16 + li];
        acc[ct] = f32x4{bv, bv, bv, bv};
    }
    for (int kt = 0; kt < KTA; ++kt) {
        int ci = kt * 4 + h;
        int q = (ci >= NOCT) ? ci - NOCT : ci;
        const us* rp = (ci >= NOCT) ? row1 : row0;
        us8 v = *(const us8*)(rp + q * 8);
        if (q == FIXQ) {
            v[0] = f2bf(__fadd_rn(bf2f(v[0]), -xn0));
            v[1] = f2bf(__fadd_rn(bf2f(v[1]), -xn1));
            v[2] = f2bf(__fadd_rn(bf2f(v[2]), -xn2));
        }
        short8 a = __builtin_bit_cast(short8, v);
        const us* wk = p.wf1a + (size_t)kt * 4096;
#pragma unroll
        for (int ct = 0; ct < 8; ++ct) {
            short8 w = *(const short8*)(wk + ((size_t)ct * 64 + lane) * 8);
            acc[ct] = __builtin_amdgcn_mfma_f32_16x16x32_bf16(a, w, acc[ct], 0, 0, 0);
        }
    }
    {   // pair-transpose epilogue -> abuf
        u32* dst = (u32*)abuf;
        int mbase = wid * 16 + (h << 2);
        int mr0 = mbase >> 1, mr1 = mr0 + 1;
#pragma unroll
        for (int ct = 0; ct < 8; ++ct) {
            f32x4 av = acc[ct];
            u32 p0 = packbf(av[0], av[1]);
            u32 p1 = packbf(av[2], av[3]);
            dst[((mr0 >> 4) * 8 + ct) * 256 + ((mr0 & 15) + ((li >> 2) << 4)) * 4 + (li & 3)] = p0;
            dst[((mr1 >> 4) * 8 + ct) * 256 + ((mr1 & 15) + ((li >> 2) << 4)) * 4 + (li & 3)] = p1;
        }
    }
    __syncthreads();

    // ---- conv-b ----
    const int mtB = wid >> 1, ctbB = (wid & 1) * 4;
    f32x4 accB[4];
#pragma unroll
    for (int cc = 0; cc < 4; ++cc) {
        float bv = p.b1b[(ctbB + cc) * 16 + li];
        accB[cc] = f32x4{bv, bv, bv, bv};
    }
    for (int kt = 0; kt < 8; ++kt) {
        short8 a = *(const short8*)(abuf + (((size_t)mtB * 8 + kt) * 64 + lane) * 8);
        const us* wk = p.wf1b + ((size_t)kt * 8 + ctbB) * 512;
#pragma unroll
        for (int cc = 0; cc < 4; ++cc) {
            short8 w = *(const short8*)(wk + ((size_t)cc * 64 + lane) * 8);
            accB[cc] = __builtin_amdgcn_mfma_f32_16x16x32_bf16(a, w, accB[cc], 0, 0, 0);
        }
    }
    {   // -> cbuf
        u32* dst = (u32*)cbuf;
        int mbase = mtB * 16 + (h << 2);
        int mr0 = mbase >> 1, mr1 = mr0 + 1;
#pragma unroll
        for (int cc = 0; cc < 4; ++cc) {
            int ct = ctbB + cc;
            f32x4 av = accB[cc];
            u32 p0 = packbf(av[0], av[1]);
            u32 p1 = packbf(av[2], av[3]);
            dst[ct * 256 + (mr0 + ((li >> 2) << 4)) * 4 + (li & 3)] = p0;
            dst[ct * 256 + (mr1 + ((li >> 2) << 4)) * 4 + (li & 3)] = p1;
        }
    }
    __syncthreads();

    // ---- conv-c -> newbf ----
    f32x4 accC[2];
#pragma unroll
    for (int cc = 0; cc < 2; ++cc) {
        float bv = p.b1c[(wid * 2 + cc) * 16 + li];
        accC[cc] = f32x4{bv, bv, bv, bv};
    }
    for (int kt = 0; kt < 8; ++kt) {
        short8 a = *(const short8*)(cbuf + ((size_t)kt * 64 + lane) * 8);
        const us* wk = p.wf1c + ((size_t)kt * 8 + wid * 2) * 512;
#pragma unroll
        for (int cc = 0; cc < 2; ++cc) {
            short8 w = *(const short8*)(wk + ((size_t)cc * 64 + lane) * 8);
            accC[cc] = __builtin_amdgcn_mfma_f32_16x16x32_bf16(a, w, accC[cc], 0, 0, 0);
        }
    }
#pragma unroll
    for (int cc = 0; cc < 2; ++cc) {
        int o = (wid * 2 + cc) * 16 + li;
#pragma unroll
        for (int r = 0; r < 4; ++r) {
            int gg = g0 + h * 4 + r;
            p.newbf[(size_t)gg * 144 + o] = f2bf(accC[cc][r]);
        }
    }
}

// ---------- stage-2 unit (r17-verbatim) ----------
__device__ void s2_unit(int uraw, const Params& p, char* smem) {
    constexpr int KTA = 9, NOCT = 18, RSTR = 144, FIXC = 128, FIXQ = 16;
    us* abuf = (us*)smem;
    us* cbuf = (us*)(smem + 16384);
    const u32* keys32 = (const u32*)p.keys;

    const int u = (int)((((u32)uraw & 7u) << 7) | ((u32)uraw >> 3));
    const int t = threadIdx.x, wid = t >> 6, lane = t & 63;
    const int li = lane & 15, h = lane >> 4;
    const int m0 = u * 64;
    const int g0 = u * 16;
    const int b = u >> 6;
    const us* fb = p.newbf + (size_t)b * NPT * RSTR;

    const int m = m0 + wid * 16 + li;
    const int g = m >> 2, pos = m & 3;
    const int J0 = (int)keys32[((size_t)g * 8 + 2 * pos) * 2];
    const int J1 = (int)keys32[((size_t)g * 8 + 2 * pos + 1) * 2];
    const int N = g & (NPT - 1);

    const us* row0 = fb + (size_t)J0 * RSTR;
    const us* row1 = fb + (size_t)J1 * RSTR;
    us8 xn8 = *(const us8*)(fb + (size_t)N * RSTR + FIXC);
    const float xn0 = bf2f(xn8[0]), xn1 = bf2f(xn8[1]), xn2 = bf2f(xn8[2]);

    __syncthreads();                     // LDS reuse guard (multi-unit stride)

    f32x4 acc[8];
#pragma unroll
    for (int ct = 0; ct < 8; ++ct) {
        float bv = p.b2a[ct * 16 + li];
        acc[ct] = f32x4{bv, bv, bv, bv};
    }
    for (int kt = 0; kt < KTA; ++kt) {
        int ci = kt * 4 + h;
        int q = (ci >= NOCT) ? ci - NOCT : ci;
        const us* rp = (ci >= NOCT) ? row1 : row0;
        us8 v = *(const us8*)(rp + q * 8);
        if (q == FIXQ) {
            v[0] = f2bf(__fadd_rn(bf2f(v[0]), -xn0));
            v[1] = f2bf(__fadd_rn(bf2f(v[1]), -xn1));
            v[2] = f2bf(__fadd_rn(bf2f(v[2]), -xn2));
        }
        short8 a = __builtin_bit_cast(short8, v);
        const us* wk = p.wf2a + (size_t)kt * 4096;
#pragma unroll
        for (int ct = 0; ct < 8; ++ct) {
            short8 w = *(const short8*)(wk + ((size_t)ct * 64 + lane) * 8);
            acc[ct] = __builtin_amdgcn_mfma_f32_16x16x32_bf16(a, w, acc[ct], 0, 0, 0);
        }
    }
    {
        u32* dst = (u32*)abuf;
        int mbase = wid * 16 + (h << 2);
        int mr0 = mbase >> 1, mr1 = mr0 + 1;
#pragma unroll
        for (int ct = 0; ct < 8; ++ct) {
            f32x4 av = acc[ct];
            u32 p0 = packbf(av[0], av[1]);
            u32 p1 = packbf(av[2], av[3]);
            dst[((mr0 >> 4) * 8 + ct) * 256 + ((mr0 & 15) + ((li >> 2) << 4)) * 4 + (li & 3)] = p0;
            dst[((mr1 >> 4) * 8 + ct) * 256 + ((mr1 & 15) + ((li >> 2) << 4)) * 4 + (li & 3)] = p1;
        }
    }
    __syncthreads();

    const int mtB = wid >> 1, ctbB = (wid & 1) * 4;
    f32x4 accB[4];
#pragma unroll
    for (int cc = 0; cc < 4; ++cc) {
        float bv = p.b2b[(ctbB + cc) * 16 + li];
        accB[cc] = f32x4{bv, bv, bv, bv};
    }
    for (int kt = 0; kt < 8; ++kt) {
        short8 a = *(const short8*)(abuf + (((size_t)mtB * 8 + kt) * 64 + lane) * 8);
        const us* wk = p.wf2b + ((size_t)kt * 8 + ctbB) * 512;
#pragma unroll
        for (int cc = 0; cc < 4; ++cc) {
            short8 w = *(const short8*)(wk + ((size_t)cc * 64 + lane) * 8);
            accB[cc] = __builtin_amdgcn_mfma_f32_16x16x32_bf16(a, w, accB[cc], 0, 0, 0);
        }
    }
    {
        u32* dst = (u32*)cbuf;
        int mbase = mtB * 16 + (h << 2);
        int mr0 = mbase >> 1, mr1 = mr0 + 1;
#pragma unroll
        for (int cc = 0; cc < 4; ++cc) {
            int ct = ctbB + cc;
            f32x4 av = accB[cc];
            u32 p0 = packbf(av[0], av[1]);
            u32 p1 = packbf(av[2], av[3]);
            dst[ct * 256 + (mr0 + ((li >> 2) << 4)) * 4 + (li & 3)] = p0;
            dst[ct * 256 + (mr1 + ((li >> 2) << 4)) * 4 + (li & 3)] = p1;
        }
    }
    __syncthreads();

    f32x4 accC[2];
#pragma unroll
    for (int cc = 0; cc < 2; ++cc) {
        float bv = p.b2c[(wid * 2 + cc) * 16 + li];
        accC[cc] = f32x4{bv, bv, bv, bv};
    }
    for (int kt = 0; kt < 8; ++kt) {
        short8 a = *(const short8*)(cbuf + ((size_t)kt * 64 + lane) * 8);
        const us* wk = p.wf2c + ((size_t)kt * 8 + wid * 2) * 512;
#pragma unroll
        for (int cc = 0; cc < 2; ++cc) {
            short8 w = *(const short8*)(wk + ((size_t)cc * 64 + lane) * 8);
            accC[cc] = __builtin_amdgcn_mfma_f32_16x16x32_bf16(a, w, accC[cc], 0, 0, 0);
        }
    }
#pragma unroll
    for (int cc = 0; cc < 2; ++cc) {
        int o = (wid * 2 + cc) * 16 + li;
#pragma unroll
        for (int r = 0; r < 4; ++r) {
            int gg = g0 + h * 4 + r;
            p.outp[(size_t)49152 + (size_t)gg * 192 + o] = fmaxf(accC[cc][r], 0.f);
        }
    }

    {   // relu(points) tail
        int r = t >> 4, q = t & 15;
        float4 v = ((const float4*)(p.pts + ((size_t)(g0 + r) << 6)))[q];
        v.x = fmaxf(v.x, 0.0f);
        v.y = fmaxf(v.y, 0.0f);
        v.z = fmaxf(v.z, 0.0f);
        v.w = fmaxf(v.w, 0.0f);
        *(float4*)(p.outp + 49152 + (size_t)(g0 + r) * 192 + 128 + q * 4) = v;
    }
}

// ---------- standalone kernels (fallback path, r17-equivalent, plain bounds) ----------
__global__ __launch_bounds__(256) void k_prep(Params p) {
    prep_unit(blockIdx.x, p);
}
__global__ __launch_bounds__(256) void k_s1(Params p) {
    __shared__ __align__(16) char smem[24576];
    __shared__ u64 kfin[16][8];
    __shared__ float snn[48];
    s1_unit(blockIdx.x, p, smem, kfin, snn);
}
__global__ __launch_bounds__(256) void k_s2(Params p) {
    __shared__ __align__(16) char smem[24576];
    s2_unit(blockIdx.x, p, smem);
}

// ---------- fused cooperative kernel ----------
// r19 experiment: (256,2). Erratum data: (256,4) pinned VGPR to 64 (=256/4,
// r7/r12). If cap = 256/N, (256,2) -> 128 VGPR -> 4 blocks/CU -> grid 1024 =
// unit count, eliminating r18's phase-tail imbalance (nb=3 -> 768 grid).
__global__ __launch_bounds__(256, 2) void k_all(Params p) {
    __shared__ __align__(16) char smem[24576];
    __shared__ u64 kfin[16][8];
    __shared__ float snn[48];
    cg::grid_group grid = cg::this_grid();
    const int gsz = (int)gridDim.x;

    for (int u = blockIdx.x; u < 268; u += gsz) prep_unit(u, p);
    grid.sync();
    for (int u = blockIdx.x; u < 1024; u += gsz) s1_unit(u, p, smem, kfin, snn);
    grid.sync();
    for (int u = blockIdx.x; u < 1024; u += gsz) s2_unit(u, p, smem);
}

extern "C" void kernel_launch(void* const* d_in, const int* in_sizes, int n_in,
                              void* d_out, int out_size, void* d_ws, size_t ws_size,
                              hipStream_t stream) {
    char* ws = (char*)d_ws;
    Params prm;
    prm.xyz = (const float*)d_in[0];
    prm.pts = (const float*)d_in[1];
    prm.w1a = (const float*)d_in[2];  prm.b1a = (const float*)d_in[3];
    prm.w1b = (const float*)d_in[4];  prm.b1b = (const float*)d_in[5];
    prm.w1c = (const float*)d_in[6];  prm.b1c = (const float*)d_in[7];
    prm.w2a = (const float*)d_in[8];  prm.b2a = (const float*)d_in[9];
    prm.w2b = (const float*)d_in[10]; prm.b2b = (const float*)d_in[11];
    prm.w2c = (const float*)d_in[12]; prm.b2c = (const float*)d_in[13];
    prm.keys  = (u64*)ws;                      // 1 MB
    prm.wf1a  = (us*)(ws + 1048576);           // 40 KB  (KT=5)
    prm.wf1b  = (us*)(ws + 1089536);           // 64 KB  (KT=8)
    prm.wf1c  = (us*)(ws + 1155072);           // 64 KB
    prm.wf2a  = (us*)(ws + 1220608);           // 72 KB  (KT=9)
    prm.wf2b  = (us*)(ws + 1294336);           // 64 KB
    prm.wf2c  = (us*)(ws + 1359872);           // 64 KB
    prm.ptsbf = (us*)(ws + 2097152);           // 16384 x 80 us = 2.62 MB
    prm.newbf = (us*)(ws + 5242880);           // 16384 x 144 us = 4.72 MB
    prm.outp  = (float*)d_out;

    // try fused cooperative launch; CHECKED, with deterministic fallback (r15 lesson)
    bool coop_ok = false;
    int nb = 0;
    hipError_t qerr = hipOccupancyMaxActiveBlocksPerMultiprocessor(
        &nb, (const void*)k_all, 256, 0);
    if (qerr == hipSuccess && nb >= 1) {
        unsigned grid = (unsigned)nb * 256u;
        if (grid > 1024u) grid = 1024u;
        void* args[] = { (void*)&prm };
        hipError_t lerr = hipLaunchCooperativeKernel((const void*)k_all, dim3(grid),
                                                     dim3(256), args, 0, stream);
        if (lerr == hipSuccess) coop_ok = true;
        else (void)hipGetLastError();          // clear sticky error state
    } else {
        (void)hipGetLastError();
    }

    if (!coop_ok) {                            // proven 3-kernel path (53.2 us)
        k_prep<<<268, 256, 0, stream>>>(prm);
        k_s1<<<1024, 256, 0, stream>>>(prm);
        k_s2<<<1024, 256, 0, stream>>>(prm);
    }
}

// Round 20
// 71.279 us; speedup vs baseline: 2.9228x; 2.9228x over previous
//
#include <hip/hip_runtime.h>
#include <stdint.h>

typedef unsigned int u32;
typedef unsigned long long u64;
typedef unsigned short us;
using short8 = __attribute__((ext_vector_type(8))) short;
using us8    = __attribute__((ext_vector_type(8))) us;
using f32x4  = __attribute__((ext_vector_type(4))) float;

#define BT 16
#define NPT 1024

struct Params {
    const float *xyz, *pts;
    const float *w1a, *b1a, *w1b, *b1b, *w1c, *b1c;
    const float *w2a, *b2a, *w2b, *b2b, *w2c, *b2c;
    u64* keys;
    us *wf1a, *wf1b, *wf1c, *wf2a, *wf2b, *wf2c, *ptsbf, *newbf;
    float* outp;
};

// ---------- bf16 helpers ----------
__device__ __forceinline__ us f2bf(float f) {           // RNE f32 -> bf16
    u32 u = __float_as_uint(f);
    u += 0x7fffu + ((u >> 16) & 1u);
    return (us)(u >> 16);
}
__device__ __forceinline__ float bf2f(us v) { return __uint_as_float(((u32)v) << 16); }
__device__ __forceinline__ u32 packbf(float lo, float hi) {  // validated software pack
    return (u32)f2bf(lo) | ((u32)f2bf(hi) << 16);            // (cvt_pk asm corrupted: r8)
}

// ---------- weight prep: conv-a layout (octet-contiguous, neighbor-split K) ----------
__device__ void wprep_a(int tid, const float* __restrict__ w, us* __restrict__ dst,
                        int Cfeat, int Creal, int NOCT) {
    int lane = tid & 63, ct = (tid >> 6) & 7, kt = tid >> 9;
    int o = ct * 16 + (lane & 15);
    int h = lane >> 4;
    int ci = kt * 4 + h;
    int p = (ci >= NOCT) ? 1 : 0;
    int q = ci - p * NOCT;
    us8 v;
#pragma unroll
    for (int j = 0; j < 8; ++j) {
        int c = q * 8 + j;
        int ref = (c < Cfeat) ? c + 3 : ((c < Cfeat + 3) ? c - Cfeat : -1);
        v[j] = (ref >= 0) ? f2bf(w[((size_t)o * Creal + ref) * 2 + p]) : (us)0;
    }
    *(us8*)(dst + (size_t)tid * 8) = v;
}

// ---------- weight prep: conv-b/c layout (pair-interleaved K, matches epilogue) ----------
__device__ void wprep_b(int tid, const float* __restrict__ w, us* __restrict__ dst) {
    int lane = tid & 63, ct = (tid >> 6) & 7, kt = tid >> 9;
    int o = ct * 16 + (lane & 15);
    int k0 = kt * 32 + ((lane >> 4) << 3);
    us8 v;
#pragma unroll
    for (int j = 0; j < 8; ++j) v[j] = f2bf(w[(size_t)o * 256 + k0 + j]);
    *(us8*)(dst + (size_t)tid * 8) = v;
}

// ---------- prep: weights | xyz copy | ptsbf rows | newbf xyz/pad ----------
__global__ __launch_bounds__(256) void k_prep(Params p) {
    const int u2 = blockIdx.x, t = threadIdx.x;
    if (u2 < 92) {
        if (u2 < 10)      wprep_a(u2 * 256 + t, p.w1a, p.wf1a, 64, 67, 10);
        else if (u2 < 26) wprep_b((u2 - 10) * 256 + t, p.w1b, p.wf1b);
        else if (u2 < 42) wprep_b((u2 - 26) * 256 + t, p.w1c, p.wf1c);
        else if (u2 < 60) wprep_a((u2 - 42) * 256 + t, p.w2a, p.wf2a, 128, 131, 18);
        else if (u2 < 76) wprep_b((u2 - 60) * 256 + t, p.w2b, p.wf2b);
        else              wprep_b((u2 - 76) * 256 + t, p.w2c, p.wf2c);
    } else if (u2 < 140) {
        int id = (u2 - 92) * 256 + t;
        ((float4*)p.outp)[id] = ((const float4*)p.xyz)[id];
    } else if (u2 < 204) {
        int r = (u2 - 140) * 256 + t;
        const float4* pr = (const float4*)(p.pts + ((size_t)r << 6));
        u32* dst = (u32*)(p.ptsbf + (size_t)r * 80);
#pragma unroll
        for (int i = 0; i < 16; ++i) {
            float4 f = pr[i];
            dst[2 * i]     = packbf(f.x, f.y);
            dst[2 * i + 1] = packbf(f.z, f.w);
        }
        const float* xr = p.xyz + (size_t)r * 3;
        dst[32] = packbf(xr[0], xr[1]);
        dst[33] = packbf(xr[2], 0.f);
#pragma unroll
        for (int i = 34; i < 40; ++i) dst[i] = 0u;
    } else {
        int r = (u2 - 204) * 256 + t;
        u32* dst = (u32*)(p.newbf + (size_t)r * 144);
        const float* xr = p.xyz + (size_t)r * 3;
        dst[64] = packbf(xr[0], xr[1]);
        dst[65] = packbf(xr[2], 0.f);
#pragma unroll
        for (int i = 66; i < 72; ++i) dst[i] = 0u;
    }
}

// ---------- stage 1: register-resident select + conv chain (r17 structure) ----------
// conv-a weight loop: unroll 4 (not 8) to cut in-flight weight regs (~16 VGPR)
// aiming for VGPR <= 128 -> 4 blocks/CU. Algorithmically identical.
__global__ __launch_bounds__(256) void k_s1(Params p) {
    constexpr int KTA = 5, NOCT = 10, RSTR = 80, FIXC = 64, FIXQ = 8;
    __shared__ __align__(16) char smem[24576];
    __shared__ u64 kfin[16][8];
    __shared__ float snn[48];
    us* abuf = (us*)smem;
    us* cbuf = (us*)(smem + 16384);

    const int u = (int)(((blockIdx.x & 7u) << 7) | (blockIdx.x >> 3));  // T1 swizzle
    const int t = threadIdx.x, wid = t >> 6, lane = t & 63;
    const int li = lane & 15, h = lane >> 4;
    const int g0 = u * 16;
    const int b = u >> 6;
    const int nb0 = g0 & (NPT - 1);
    const float* xg = p.xyz + (size_t)b * 3072;
    const us* fb = p.ptsbf + (size_t)b * NPT * RSTR;

    // ---- one-time: this lane's 4 j-points into registers ----
    const int j0 = (wid << 8) + (lane << 2);
    float4 c0 = *(const float4*)(xg + (size_t)j0 * 3);
    float4 c1 = *(const float4*)(xg + (size_t)j0 * 3 + 4);
    float4 c2 = *(const float4*)(xg + (size_t)j0 * 3 + 8);
    const float jxc[4] = {c0.x, c0.w, c1.z, c2.y};
    const float jyc[4] = {c0.y, c1.x, c1.w, c2.z};
    const float jzc[4] = {c0.z, c1.y, c2.x, c2.w};

    if (t < 48) snn[t] = xg[(size_t)nb0 * 3 + t];
    if (t < 128)
        kfin[t >> 3][t & 7] = ((u64)__float_as_uint(0.04f) << 32) | (u32)(nb0 + (t >> 3));
    __syncthreads();

    // ---- select sweep: 16 n x 4 register-j per lane ----
    for (int i = 0; i < 16; ++i) {
        const float xn = snn[i * 3], yn = snn[i * 3 + 1], zn = snn[i * 3 + 2];
#pragma unroll
        for (int jj = 0; jj < 4; ++jj) {
            float dx = __fadd_rn(jxc[jj], -xn);
            float dy = __fadd_rn(jyc[jj], -yn);
            float dz = __fadd_rn(jzc[jj], -zn);
            // exact IEEE f32, no contraction: must match numpy bit-for-bit
            float d = __fadd_rn(__fadd_rn(__fmul_rn(dx, dx), __fmul_rn(dy, dy)),
                                __fmul_rn(dz, dz));
            if (d > 1e-10f && d < 0.04f) {
                int oct = ((int)__fadd_rn(dx, 1.0f)) * 4 + ((int)__fadd_rn(dy, 1.0f)) * 2 +
                          ((int)__fadd_rn(dz, 1.0f));
                u64 key = ((u64)__float_as_uint(d) << 32) | (u32)(j0 + jj);
                atomicMin(&kfin[i][oct], key);
            }
        }
    }
    __syncthreads();

    // ---- publish keys for stage 2 + extract this thread's J's ----
    if (t < 128)
        p.keys[(((size_t)g0 + (t >> 3)) << 3) + (t & 7)] = kfin[t >> 3][t & 7];
    const int n_loc_c = wid * 4 + (li >> 2), pos = li & 3;
    const int J0 = (int)(u32)kfin[n_loc_c][2 * pos];
    const int J1 = (int)(u32)kfin[n_loc_c][2 * pos + 1];
    const int N = nb0 + n_loc_c;
    __syncthreads();

    const us* row0 = fb + (size_t)J0 * RSTR;
    const us* row1 = fb + (size_t)J1 * RSTR;
    us8 xn8 = *(const us8*)(fb + (size_t)N * RSTR + FIXC);
    const float xn0 = bf2f(xn8[0]), xn1 = bf2f(xn8[1]), xn2 = bf2f(xn8[2]);

    // ---- conv-a ----
    f32x4 acc[8];
#pragma unroll
    for (int ct = 0; ct < 8; ++ct) {
        float bv = p.b1a[ct * 16 + li];
        acc[ct] = f32x4{bv, bv, bv, bv};
    }
    for (int kt = 0; kt < KTA; ++kt) {
        int ci = kt * 4 + h;
        int q = (ci >= NOCT) ? ci - NOCT : ci;
        const us* rp = (ci >= NOCT) ? row1 : row0;
        us8 v = *(const us8*)(rp + q * 8);
        if (q == FIXQ) {
            v[0] = f2bf(__fadd_rn(bf2f(v[0]), -xn0));
            v[1] = f2bf(__fadd_rn(bf2f(v[1]), -xn1));
            v[2] = f2bf(__fadd_rn(bf2f(v[2]), -xn2));
        }
        short8 a = __builtin_bit_cast(short8, v);
        const us* wk = p.wf1a + (size_t)kt * 4096;
#pragma unroll 4
        for (int ct = 0; ct < 8; ++ct) {
            short8 w = *(const short8*)(wk + ((size_t)ct * 64 + lane) * 8);
            acc[ct] = __builtin_amdgcn_mfma_f32_16x16x32_bf16(a, w, acc[ct], 0, 0, 0);
        }
    }
    {   // pair-transpose epilogue -> abuf
        u32* dst = (u32*)abuf;
        int mbase = wid * 16 + (h << 2);
        int mr0 = mbase >> 1, mr1 = mr0 + 1;
#pragma unroll
        for (int ct = 0; ct < 8; ++ct) {
            f32x4 av = acc[ct];
            u32 p0 = packbf(av[0], av[1]);
            u32 p1 = packbf(av[2], av[3]);
            dst[((mr0 >> 4) * 8 + ct) * 256 + ((mr0 & 15) + ((li >> 2) << 4)) * 4 + (li & 3)] = p0;
            dst[((mr1 >> 4) * 8 + ct) * 256 + ((mr1 & 15) + ((li >> 2) << 4)) * 4 + (li & 3)] = p1;
        }
    }
    __syncthreads();

    // ---- conv-b ----
    const int mtB = wid >> 1, ctbB = (wid & 1) * 4;
    f32x4 accB[4];
#pragma unroll
    for (int cc = 0; cc < 4; ++cc) {
        float bv = p.b1b[(ctbB + cc) * 16 + li];
        accB[cc] = f32x4{bv, bv, bv, bv};
    }
    for (int kt = 0; kt < 8; ++kt) {
        short8 a = *(const short8*)(abuf + (((size_t)mtB * 8 + kt) * 64 + lane) * 8);
        const us* wk = p.wf1b + ((size_t)kt * 8 + ctbB) * 512;
#pragma unroll
        for (int cc = 0; cc < 4; ++cc) {
            short8 w = *(const short8*)(wk + ((size_t)cc * 64 + lane) * 8);
            accB[cc] = __builtin_amdgcn_mfma_f32_16x16x32_bf16(a, w, accB[cc], 0, 0, 0);
        }
    }
    {   // -> cbuf
        u32* dst = (u32*)cbuf;
        int mbase = mtB * 16 + (h << 2);
        int mr0 = mbase >> 1, mr1 = mr0 + 1;
#pragma unroll
        for (int cc = 0; cc < 4; ++cc) {
            int ct = ctbB + cc;
            f32x4 av = accB[cc];
            u32 p0 = packbf(av[0], av[1]);
            u32 p1 = packbf(av[2], av[3]);
            dst[ct * 256 + (mr0 + ((li >> 2) << 4)) * 4 + (li & 3)] = p0;
            dst[ct * 256 + (mr1 + ((li >> 2) << 4)) * 4 + (li & 3)] = p1;
        }
    }
    __syncthreads();

    // ---- conv-c -> newbf ----
    f32x4 accC[2];
#pragma unroll
    for (int cc = 0; cc < 2; ++cc) {
        float bv = p.b1c[(wid * 2 + cc) * 16 + li];
        accC[cc] = f32x4{bv, bv, bv, bv};
    }
    for (int kt = 0; kt < 8; ++kt) {
        short8 a = *(const short8*)(cbuf + ((size_t)kt * 64 + lane) * 8);
        const us* wk = p.wf1c + ((size_t)kt * 8 + wid * 2) * 512;
#pragma unroll
        for (int cc = 0; cc < 2; ++cc) {
            short8 w = *(const short8*)(wk + ((size_t)cc * 64 + lane) * 8);
            accC[cc] = __builtin_amdgcn_mfma_f32_16x16x32_bf16(a, w, accC[cc], 0, 0, 0);
        }
    }
#pragma unroll
    for (int cc = 0; cc < 2; ++cc) {
        int o = (wid * 2 + cc) * 16 + li;
#pragma unroll
        for (int r = 0; r < 4; ++r) {
            int gg = g0 + h * 4 + r;
            p.newbf[(size_t)gg * 144 + o] = f2bf(accC[cc][r]);
        }
    }
}

// ---------- stage 2 (r17 structure; conv-a weight loop unroll 4) ----------
__global__ __launch_bounds__(256) void k_s2(Params p) {
    constexpr int KTA = 9, NOCT = 18, RSTR = 144, FIXC = 128, FIXQ = 16;
    __shared__ __align__(16) char smem[24576];
    us* abuf = (us*)smem;
    us* cbuf = (us*)(smem + 16384);
    const u32* keys32 = (const u32*)p.keys;

    const int u = (int)(((blockIdx.x & 7u) << 7) | (blockIdx.x >> 3));
    const int t = threadIdx.x, wid = t >> 6, lane = t & 63;
    const int li = lane & 15, h = lane >> 4;
    const int m0 = u * 64;
    const int g0 = u * 16;
    const int b = u >> 6;
    const us* fb = p.newbf + (size_t)b * NPT * RSTR;

    const int m = m0 + wid * 16 + li;
    const int g = m >> 2, pos = m & 3;
    const int J0 = (int)keys32[((size_t)g * 8 + 2 * pos) * 2];
    const int J1 = (int)keys32[((size_t)g * 8 + 2 * pos + 1) * 2];
    const int N = g & (NPT - 1);

    const us* row0 = fb + (size_t)J0 * RSTR;
    const us* row1 = fb + (size_t)J1 * RSTR;
    us8 xn8 = *(const us8*)(fb + (size_t)N * RSTR + FIXC);
    const float xn0 = bf2f(xn8[0]), xn1 = bf2f(xn8[1]), xn2 = bf2f(xn8[2]);

    f32x4 acc[8];
#pragma unroll
    for (int ct = 0; ct < 8; ++ct) {
        float bv = p.b2a[ct * 16 + li];
        acc[ct] = f32x4{bv, bv, bv, bv};
    }
    for (int kt = 0; kt < KTA; ++kt) {
        int ci = kt * 4 + h;
        int q = (ci >= NOCT) ? ci - NOCT : ci;
        const us* rp = (ci >= NOCT) ? row1 : row0;
        us8 v = *(const us8*)(rp + q * 8);
        if (q == FIXQ) {
            v[0] = f2bf(__fadd_rn(bf2f(v[0]), -xn0));
            v[1] = f2bf(__fadd_rn(bf2f(v[1]), -xn1));
            v[2] = f2bf(__fadd_rn(bf2f(v[2]), -xn2));
        }
        short8 a = __builtin_bit_cast(short8, v);
        const us* wk = p.wf2a + (size_t)kt * 4096;
#pragma unroll 4
        for (int ct = 0; ct < 8; ++ct) {
            short8 w = *(const short8*)(wk + ((size_t)ct * 64 + lane) * 8);
            acc[ct] = __builtin_amdgcn_mfma_f32_16x16x32_bf16(a, w, acc[ct], 0, 0, 0);
        }
    }
    {
        u32* dst = (u32*)abuf;
        int mbase = wid * 16 + (h << 2);
        int mr0 = mbase >> 1, mr1 = mr0 + 1;
#pragma unroll
        for (int ct = 0; ct < 8; ++ct) {
            f32x4 av = acc[ct];
            u32 p0 = packbf(av[0], av[1]);
            u32 p1 = packbf(av[2], av[3]);
            dst[((mr0 >> 4) * 8 + ct) * 256 + ((mr0 & 15) + ((li >> 2) << 4)) * 4 + (li & 3)] = p0;
            dst[((mr1 >> 4) * 8 + ct) * 256 + ((mr1 & 15) + ((li >> 2) << 4)) * 4 + (li & 3)] = p1;
        }
    }
    __syncthreads();

    const int mtB = wid >> 1, ctbB = (wid & 1) * 4;
    f32x4 accB[4];
#pragma unroll
    for (int cc = 0; cc < 4; ++cc) {
        float bv = p.b2b[(ctbB + cc) * 16 + li];
        accB[cc] = f32x4{bv, bv, bv, bv};
    }
    for (int kt = 0; kt < 8; ++kt) {
        short8 a = *(const short8*)(abuf + (((size_t)mtB * 8 + kt) * 64 + lane) * 8);
        const us* wk = p.wf2b + ((size_t)kt * 8 + ctbB) * 512;
#pragma unroll
        for (int cc = 0; cc < 4; ++cc) {
            short8 w = *(const short8*)(wk + ((size_t)cc * 64 + lane) * 8);
            accB[cc] = __builtin_amdgcn_mfma_f32_16x16x32_bf16(a, w, accB[cc], 0, 0, 0);
        }
    }
    {
        u32* dst = (u32*)cbuf;
        int mbase = mtB * 16 + (h << 2);
        int mr0 = mbase >> 1, mr1 = mr0 + 1;
#pragma unroll
        for (int cc = 0; cc < 4; ++cc) {
            int ct = ctbB + cc;
            f32x4 av = accB[cc];
            u32 p0 = packbf(av[0], av[1]);
            u32 p1 = packbf(av[2], av[3]);
            dst[ct * 256 + (mr0 + ((li >> 2) << 4)) * 4 + (li & 3)] = p0;
            dst[ct * 256 + (mr1 + ((li >> 2) << 4)) * 4 + (li & 3)] = p1;
        }
    }
    __syncthreads();

    f32x4 accC[2];
#pragma unroll
    for (int cc = 0; cc < 2; ++cc) {
        float bv = p.b2c[(wid * 2 + cc) * 16 + li];
        accC[cc] = f32x4{bv, bv, bv, bv};
    }
    for (int kt = 0; kt < 8; ++kt) {
        short8 a = *(const short8*)(cbuf + ((size_t)kt * 64 + lane) * 8);
        const us* wk = p.wf2c + ((size_t)kt * 8 + wid * 2) * 512;
#pragma unroll
        for (int cc = 0; cc < 2; ++cc) {
            short8 w = *(const short8*)(wk + ((size_t)cc * 64 + lane) * 8);
            accC[cc] = __builtin_amdgcn_mfma_f32_16x16x32_bf16(a, w, accC[cc], 0, 0, 0);
        }
    }
#pragma unroll
    for (int cc = 0; cc < 2; ++cc) {
        int o = (wid * 2 + cc) * 16 + li;
#pragma unroll
        for (int r = 0; r < 4; ++r) {
            int gg = g0 + h * 4 + r;
            p.outp[(size_t)49152 + (size_t)gg * 192 + o] = fmaxf(accC[cc][r], 0.f);
        }
    }

    {   // relu(points) tail
        int r = t >> 4, q = t & 15;
        float4 v = ((const float4*)(p.pts + ((size_t)(g0 + r) << 6)))[q];
        v.x = fmaxf(v.x, 0.0f);
        v.y = fmaxf(v.y, 0.0f);
        v.z = fmaxf(v.z, 0.0f);
        v.w = fmaxf(v.w, 0.0f);
        *(float4*)(p.outp + 49152 + (size_t)(g0 + r) * 192 + 128 + q * 4) = v;
    }
}

extern "C" void kernel_launch(void* const* d_in, const int* in_sizes, int n_in,
                              void* d_out, int out_size, void* d_ws, size_t ws_size,
                              hipStream_t stream) {
    char* ws = (char*)d_ws;
    Params prm;
    prm.xyz = (const float*)d_in[0];
    prm.pts = (const float*)d_in[1];
    prm.w1a = (const float*)d_in[2];  prm.b1a = (const float*)d_in[3];
    prm.w1b = (const float*)d_in[4];  prm.b1b = (const float*)d_in[5];
    prm.w1c = (const float*)d_in[6];  prm.b1c = (const float*)d_in[7];
    prm.w2a = (const float*)d_in[8];  prm.b2a = (const float*)d_in[9];
    prm.w2b = (const float*)d_in[10]; prm.b2b = (const float*)d_in[11];
    prm.w2c = (const float*)d_in[12]; prm.b2c = (const float*)d_in[13];
    prm.keys  = (u64*)ws;                      // 1 MB
    prm.wf1a  = (us*)(ws + 1048576);           // 40 KB  (KT=5)
    prm.wf1b  = (us*)(ws + 1089536);           // 64 KB  (KT=8)
    prm.wf1c  = (us*)(ws + 1155072);           // 64 KB
    prm.wf2a  = (us*)(ws + 1220608);           // 72 KB  (KT=9)
    prm.wf2b  = (us*)(ws + 1294336);           // 64 KB
    prm.wf2c  = (us*)(ws + 1359872);           // 64 KB
    prm.ptsbf = (us*)(ws + 2097152);           // 16384 x 80 us = 2.62 MB
    prm.newbf = (us*)(ws + 5242880);           // 16384 x 144 us = 4.72 MB
    prm.outp  = (float*)d_out;

    k_prep<<<268, 256, 0, stream>>>(prm);
    k_s1<<<1024, 256, 0, stream>>>(prm);
    k_s2<<<1024, 256, 0, stream>>>(prm);
}

// Round 21
// 53.039 us; speedup vs baseline: 3.9279x; 1.3439x over previous
//
#include <hip/hip_runtime.h>
#include <stdint.h>

typedef unsigned int u32;
typedef unsigned long long u64;
typedef unsigned short us;
using short8 = __attribute__((ext_vector_type(8))) short;
using us8    = __attribute__((ext_vector_type(8))) us;
using f32x4  = __attribute__((ext_vector_type(4))) float;

#define BT 16
#define NPT 1024

// ---------- bf16 helpers ----------
__device__ __forceinline__ us f2bf(float f) {           // RNE f32 -> bf16
    u32 u = __float_as_uint(f);
    u += 0x7fffu + ((u >> 16) & 1u);
    return (us)(u >> 16);
}
__device__ __forceinline__ float bf2f(us v) { return __uint_as_float(((u32)v) << 16); }
__device__ __forceinline__ u32 packbf(float lo, float hi) {  // validated software pack
    return (u32)f2bf(lo) | ((u32)f2bf(hi) << 16);            // (cvt_pk asm corrupted: r8)
}

// ---------- weight prep: conv-a layout (octet-contiguous, neighbor-split K) ----------
__device__ void wprep_a(int tid, const float* __restrict__ w, us* __restrict__ dst,
                        int Cfeat, int Creal, int NOCT) {
    int lane = tid & 63, ct = (tid >> 6) & 7, kt = tid >> 9;
    int o = ct * 16 + (lane & 15);
    int h = lane >> 4;
    int ci = kt * 4 + h;
    int p = (ci >= NOCT) ? 1 : 0;
    int q = ci - p * NOCT;
    us8 v;
#pragma unroll
    for (int j = 0; j < 8; ++j) {
        int c = q * 8 + j;
        int ref = (c < Cfeat) ? c + 3 : ((c < Cfeat + 3) ? c - Cfeat : -1);
        v[j] = (ref >= 0) ? f2bf(w[((size_t)o * Creal + ref) * 2 + p]) : (us)0;
    }
    *(us8*)(dst + (size_t)tid * 8) = v;
}

// ---------- weight prep: conv-b/c layout (pair-interleaved K, matches epilogue) ----------
__device__ void wprep_b(int tid, const float* __restrict__ w, us* __restrict__ dst) {
    int lane = tid & 63, ct = (tid >> 6) & 7, kt = tid >> 9;
    int o = ct * 16 + (lane & 15);
    int k0 = kt * 32 + ((lane >> 4) << 3);
    us8 v;
#pragma unroll
    for (int j = 0; j < 8; ++j) v[j] = f2bf(w[(size_t)o * 256 + k0 + j]);
    *(us8*)(dst + (size_t)tid * 8) = v;
}

// ---------- prep: weights | xyz copy | ptsbf rows | newbf xyz/pad ----------
__global__ __launch_bounds__(256) void k_prep(
    const float* __restrict__ xyz, const float* __restrict__ pts,
    const float* __restrict__ w1a, us* __restrict__ f1a,
    const float* __restrict__ w1b, us* __restrict__ f1b,
    const float* __restrict__ w1c, us* __restrict__ f1c,
    const float* __restrict__ w2a, us* __restrict__ f2a,
    const float* __restrict__ w2b, us* __restrict__ f2b,
    const float* __restrict__ w2c, us* __restrict__ f2c,
    us* __restrict__ ptsbf, us* __restrict__ newbf, float* __restrict__ outp) {
    const int u2 = blockIdx.x, t = threadIdx.x;
    if (u2 < 92) {
        if (u2 < 10)      wprep_a(u2 * 256 + t, w1a, f1a, 64, 67, 10);
        else if (u2 < 26) wprep_b((u2 - 10) * 256 + t, w1b, f1b);
        else if (u2 < 42) wprep_b((u2 - 26) * 256 + t, w1c, f1c);
        else if (u2 < 60) wprep_a((u2 - 42) * 256 + t, w2a, f2a, 128, 131, 18);
        else if (u2 < 76) wprep_b((u2 - 60) * 256 + t, w2b, f2b);
        else              wprep_b((u2 - 76) * 256 + t, w2c, f2c);
    } else if (u2 < 140) {
        int id = (u2 - 92) * 256 + t;
        ((float4*)outp)[id] = ((const float4*)xyz)[id];
    } else if (u2 < 204) {
        int r = (u2 - 140) * 256 + t;
        const float4* pr = (const float4*)(pts + ((size_t)r << 6));
        u32* dst = (u32*)(ptsbf + (size_t)r * 80);
#pragma unroll
        for (int i = 0; i < 16; ++i) {
            float4 f = pr[i];
            dst[2 * i]     = packbf(f.x, f.y);
            dst[2 * i + 1] = packbf(f.z, f.w);
        }
        const float* xr = xyz + (size_t)r * 3;
        dst[32] = packbf(xr[0], xr[1]);
        dst[33] = packbf(xr[2], 0.f);
#pragma unroll
        for (int i = 34; i < 40; ++i) dst[i] = 0u;
    } else {
        int r = (u2 - 204) * 256 + t;
        u32* dst = (u32*)(newbf + (size_t)r * 144);
        const float* xr = xyz + (size_t)r * 3;
        dst[64] = packbf(xr[0], xr[1]);
        dst[65] = packbf(xr[2], 0.f);
#pragma unroll
        for (int i = 66; i < 72; ++i) dst[i] = 0u;
    }
}

// ---------- stage 1: register-resident select + conv chain ----------
// Select (r17): each lane holds 4 j-points' coords in 12 REGISTERS (one-time
// coalesced load); 4 waves x 256-j chunks sweep the block's 16 n with pure
// VALU (exact __fadd_rn/__fmul_rn + (int)(d+1.0f) octant); valid hits (~3.4%)
// atomicMin directly into LDS kfin (order-independent exact tie-break).
__global__ __launch_bounds__(256) void k_s1(
    const float* __restrict__ xyz, const us* __restrict__ ptsbf,
    u64* __restrict__ keys,
    const us* __restrict__ wfa, const float* __restrict__ ba,
    const us* __restrict__ wfb, const float* __restrict__ bb,
    const us* __restrict__ wfc, const float* __restrict__ bc,
    us* __restrict__ newbf_out) {
    constexpr int KTA = 5, NOCT = 10, RSTR = 80, FIXC = 64, FIXQ = 8;
    __shared__ __align__(16) char smem[24576];   // abuf(16K)+cbuf(8K)
    __shared__ u64 kfin[16][8];
    __shared__ float snn[48];
    us* abuf = (us*)smem;
    us* cbuf = (us*)(smem + 16384);

    const int u = (int)(((blockIdx.x & 7u) << 7) | (blockIdx.x >> 3));  // T1 swizzle
    const int t = threadIdx.x, wid = t >> 6, lane = t & 63;
    const int li = lane & 15, h = lane >> 4;
    const int g0 = u * 16;               // global group base
    const int b = u >> 6;
    const int nb0 = g0 & (NPT - 1);      // batch-local base (16-aligned)
    const float* xg = xyz + (size_t)b * 3072;
    const us* fb = ptsbf + (size_t)b * NPT * RSTR;

    // ---- one-time: this lane's 4 j-points into registers ----
    const int j0 = (wid << 8) + (lane << 2);
    float4 c0 = *(const float4*)(xg + (size_t)j0 * 3);
    float4 c1 = *(const float4*)(xg + (size_t)j0 * 3 + 4);
    float4 c2 = *(const float4*)(xg + (size_t)j0 * 3 + 8);
    const float jxc[4] = {c0.x, c0.w, c1.z, c2.y};
    const float jyc[4] = {c0.y, c1.x, c1.w, c2.z};
    const float jzc[4] = {c0.z, c1.y, c2.x, c2.w};

    if (t < 48) snn[t] = xg[(size_t)nb0 * 3 + t];
    if (t < 128)
        kfin[t >> 3][t & 7] = ((u64)__float_as_uint(0.04f) << 32) | (u32)(nb0 + (t >> 3));
    __syncthreads();

    // ---- select sweep: 16 n x 4 register-j per lane ----
    for (int i = 0; i < 16; ++i) {
        const float xn = snn[i * 3], yn = snn[i * 3 + 1], zn = snn[i * 3 + 2];
#pragma unroll
        for (int jj = 0; jj < 4; ++jj) {
            float dx = __fadd_rn(jxc[jj], -xn);
            float dy = __fadd_rn(jyc[jj], -yn);
            float dz = __fadd_rn(jzc[jj], -zn);
            // exact IEEE f32, no contraction: must match numpy bit-for-bit
            float d = __fadd_rn(__fadd_rn(__fmul_rn(dx, dx), __fmul_rn(dy, dy)),
                                __fmul_rn(dz, dz));
            if (d > 1e-10f && d < 0.04f) {
                // valid => |dx|,|dy|,|dz| < 0.2 => (int)(dx+1) in {0,1}: oct in [0,8)
                int oct = ((int)__fadd_rn(dx, 1.0f)) * 4 + ((int)__fadd_rn(dy, 1.0f)) * 2 +
                          ((int)__fadd_rn(dz, 1.0f));
                u64 key = ((u64)__float_as_uint(d) << 32) | (u32)(j0 + jj);
                atomicMin(&kfin[i][oct], key);
            }
        }
    }
    __syncthreads();

    // ---- publish keys for stage 2 + extract this thread's J's ----
    if (t < 128)
        keys[(((size_t)g0 + (t >> 3)) << 3) + (t & 7)] = kfin[t >> 3][t & 7];
    const int n_loc_c = wid * 4 + (li >> 2), pos = li & 3;
    const int J0 = (int)(u32)kfin[n_loc_c][2 * pos];
    const int J1 = (int)(u32)kfin[n_loc_c][2 * pos + 1];
    const int N = nb0 + n_loc_c;
    __syncthreads();

    const us* row0 = fb + (size_t)J0 * RSTR;
    const us* row1 = fb + (size_t)J1 * RSTR;
    us8 xn8 = *(const us8*)(fb + (size_t)N * RSTR + FIXC);
    const float xn0 = bf2f(xn8[0]), xn1 = bf2f(xn8[1]), xn2 = bf2f(xn8[2]);

    // ---- conv-a (r14-verbatim) ----
    f32x4 acc[8];
#pragma unroll
    for (int ct = 0; ct < 8; ++ct) {
        float bv = ba[ct * 16 + li];
        acc[ct] = f32x4{bv, bv, bv, bv};
    }
    for (int kt = 0; kt < KTA; ++kt) {
        int ci = kt * 4 + h;
        int q = (ci >= NOCT) ? ci - NOCT : ci;
        const us* rp = (ci >= NOCT) ? row1 : row0;
        us8 v = *(const us8*)(rp + q * 8);
        if (q == FIXQ) {
            v[0] = f2bf(__fadd_rn(bf2f(v[0]), -xn0));
            v[1] = f2bf(__fadd_rn(bf2f(v[1]), -xn1));
            v[2] = f2bf(__fadd_rn(bf2f(v[2]), -xn2));
        }
        short8 a = __builtin_bit_cast(short8, v);
        const us* wk = wfa + (size_t)kt * 4096;
#pragma unroll
        for (int ct = 0; ct < 8; ++ct) {
            short8 w = *(const short8*)(wk + ((size_t)ct * 64 + lane) * 8);
            acc[ct] = __builtin_amdgcn_mfma_f32_16x16x32_bf16(a, w, acc[ct], 0, 0, 0);
        }
    }
    {   // pair-transpose epilogue -> abuf
        u32* dst = (u32*)abuf;
        int mbase = wid * 16 + (h << 2);
        int mr0 = mbase >> 1, mr1 = mr0 + 1;
#pragma unroll
        for (int ct = 0; ct < 8; ++ct) {
            f32x4 av = acc[ct];
            u32 p0 = packbf(av[0], av[1]);
            u32 p1 = packbf(av[2], av[3]);
            dst[((mr0 >> 4) * 8 + ct) * 256 + ((mr0 & 15) + ((li >> 2) << 4)) * 4 + (li & 3)] = p0;
            dst[((mr1 >> 4) * 8 + ct) * 256 + ((mr1 & 15) + ((li >> 2) << 4)) * 4 + (li & 3)] = p1;
        }
    }
    __syncthreads();

    // ---- conv-b ----
    const int mtB = wid >> 1, ctbB = (wid & 1) * 4;
    f32x4 accB[4];
#pragma unroll
    for (int cc = 0; cc < 4; ++cc) {
        float bv = bb[(ctbB + cc) * 16 + li];
        accB[cc] = f32x4{bv, bv, bv, bv};
    }
    for (int kt = 0; kt < 8; ++kt) {
        short8 a = *(const short8*)(abuf + (((size_t)mtB * 8 + kt) * 64 + lane) * 8);
        const us* wk = wfb + ((size_t)kt * 8 + ctbB) * 512;
#pragma unroll
        for (int cc = 0; cc < 4; ++cc) {
            short8 w = *(const short8*)(wk + ((size_t)cc * 64 + lane) * 8);
            accB[cc] = __builtin_amdgcn_mfma_f32_16x16x32_bf16(a, w, accB[cc], 0, 0, 0);
        }
    }
    {   // -> cbuf
        u32* dst = (u32*)cbuf;
        int mbase = mtB * 16 + (h << 2);
        int mr0 = mbase >> 1, mr1 = mr0 + 1;
#pragma unroll
        for (int cc = 0; cc < 4; ++cc) {
            int ct = ctbB + cc;
            f32x4 av = accB[cc];
            u32 p0 = packbf(av[0], av[1]);
            u32 p1 = packbf(av[2], av[3]);
            dst[ct * 256 + (mr0 + ((li >> 2) << 4)) * 4 + (li & 3)] = p0;
            dst[ct * 256 + (mr1 + ((li >> 2) << 4)) * 4 + (li & 3)] = p1;
        }
    }
    __syncthreads();

    // ---- conv-c -> newbf ----
    f32x4 accC[2];
#pragma unroll
    for (int cc = 0; cc < 2; ++cc) {
        float bv = bc[(wid * 2 + cc) * 16 + li];
        accC[cc] = f32x4{bv, bv, bv, bv};
    }
    for (int kt = 0; kt < 8; ++kt) {
        short8 a = *(const short8*)(cbuf + ((size_t)kt * 64 + lane) * 8);
        const us* wk = wfc + ((size_t)kt * 8 + wid * 2) * 512;
#pragma unroll
        for (int cc = 0; cc < 2; ++cc) {
            short8 w = *(const short8*)(wk + ((size_t)cc * 64 + lane) * 8);
            accC[cc] = __builtin_amdgcn_mfma_f32_16x16x32_bf16(a, w, accC[cc], 0, 0, 0);
        }
    }
#pragma unroll
    for (int cc = 0; cc < 2; ++cc) {
        int o = (wid * 2 + cc) * 16 + li;
#pragma unroll
        for (int r = 0; r < 4; ++r) {
            int gg = g0 + h * 4 + r;
            newbf_out[(size_t)gg * 144 + o] = f2bf(accC[cc][r]);
        }
    }
}

// ---------- stage 2 (r14-verbatim) ----------
__global__ __launch_bounds__(256) void k_s2(
    const float* __restrict__ pts, const us* __restrict__ feat,
    const u32* __restrict__ keys32,
    const us* __restrict__ wfa, const float* __restrict__ ba,
    const us* __restrict__ wfb, const float* __restrict__ bb,
    const us* __restrict__ wfc, const float* __restrict__ bc,
    float* __restrict__ outp) {
    constexpr int KTA = 9, NOCT = 18, RSTR = 144, FIXC = 128, FIXQ = 16;
    __shared__ us abuf[2 * 8 * 512];
    __shared__ us cbuf[1 * 8 * 512];

    const int u = (int)(((blockIdx.x & 7u) << 7) | (blockIdx.x >> 3));
    const int t = threadIdx.x, wid = t >> 6, lane = t & 63;
    const int li = lane & 15, h = lane >> 4;
    const int m0 = u * 64;
    const int g0 = u * 16;
    const int b = u >> 6;
    const us* fb = feat + (size_t)b * NPT * RSTR;

    const int m = m0 + wid * 16 + li;
    const int g = m >> 2, pos = m & 3;
    const int J0 = (int)keys32[((size_t)g * 8 + 2 * pos) * 2];
    const int J1 = (int)keys32[((size_t)g * 8 + 2 * pos + 1) * 2];
    const int N = g & (NPT - 1);

    const us* row0 = fb + (size_t)J0 * RSTR;
    const us* row1 = fb + (size_t)J1 * RSTR;
    us8 xn8 = *(const us8*)(fb + (size_t)N * RSTR + FIXC);
    const float xn0 = bf2f(xn8[0]), xn1 = bf2f(xn8[1]), xn2 = bf2f(xn8[2]);

    f32x4 acc[8];
#pragma unroll
    for (int ct = 0; ct < 8; ++ct) {
        float bv = ba[ct * 16 + li];
        acc[ct] = f32x4{bv, bv, bv, bv};
    }
    for (int kt = 0; kt < KTA; ++kt) {
        int ci = kt * 4 + h;
        int q = (ci >= NOCT) ? ci - NOCT : ci;
        const us* rp = (ci >= NOCT) ? row1 : row0;
        us8 v = *(const us8*)(rp + q * 8);
        if (q == FIXQ) {
            v[0] = f2bf(__fadd_rn(bf2f(v[0]), -xn0));
            v[1] = f2bf(__fadd_rn(bf2f(v[1]), -xn1));
            v[2] = f2bf(__fadd_rn(bf2f(v[2]), -xn2));
        }
        short8 a = __builtin_bit_cast(short8, v);
        const us* wk = wfa + (size_t)kt * 4096;
#pragma unroll
        for (int ct = 0; ct < 8; ++ct) {
            short8 w = *(const short8*)(wk + ((size_t)ct * 64 + lane) * 8);
            acc[ct] = __builtin_amdgcn_mfma_f32_16x16x32_bf16(a, w, acc[ct], 0, 0, 0);
        }
    }
    {
        u32* dst = (u32*)abuf;
        int mbase = wid * 16 + (h << 2);
        int mr0 = mbase >> 1, mr1 = mr0 + 1;
#pragma unroll
        for (int ct = 0; ct < 8; ++ct) {
            f32x4 av = acc[ct];
            u32 p0 = packbf(av[0], av[1]);
            u32 p1 = packbf(av[2], av[3]);
            dst[((mr0 >> 4) * 8 + ct) * 256 + ((mr0 & 15) + ((li >> 2) << 4)) * 4 + (li & 3)] = p0;
            dst[((mr1 >> 4) * 8 + ct) * 256 + ((mr1 & 15) + ((li >> 2) << 4)) * 4 + (li & 3)] = p1;
        }
    }
    __syncthreads();

    const int mtB = wid >> 1, ctbB = (wid & 1) * 4;
    f32x4 accB[4];
#pragma unroll
    for (int cc = 0; cc < 4; ++cc) {
        float bv = bb[(ctbB + cc) * 16 + li];
        accB[cc] = f32x4{bv, bv, bv, bv};
    }
    for (int kt = 0; kt < 8; ++kt) {
        short8 a = *(const short8*)(abuf + (((size_t)mtB * 8 + kt) * 64 + lane) * 8);
        const us* wk = wfb + ((size_t)kt * 8 + ctbB) * 512;
#pragma unroll
        for (int cc = 0; cc < 4; ++cc) {
            short8 w = *(const short8*)(wk + ((size_t)cc * 64 + lane) * 8);
            accB[cc] = __builtin_amdgcn_mfma_f32_16x16x32_bf16(a, w, accB[cc], 0, 0, 0);
        }
    }
    {
        u32* dst = (u32*)cbuf;
        int mbase = mtB * 16 + (h << 2);
        int mr0 = mbase >> 1, mr1 = mr0 + 1;
#pragma unroll
        for (int cc = 0; cc < 4; ++cc) {
            int ct = ctbB + cc;
            f32x4 av = accB[cc];
            u32 p0 = packbf(av[0], av[1]);
            u32 p1 = packbf(av[2], av[3]);
            dst[ct * 256 + (mr0 + ((li >> 2) << 4)) * 4 + (li & 3)] = p0;
            dst[ct * 256 + (mr1 + ((li >> 2) << 4)) * 4 + (li & 3)] = p1;
        }
    }
    __syncthreads();

    f32x4 accC[2];
#pragma unroll
    for (int cc = 0; cc < 2; ++cc) {
        float bv = bc[(wid * 2 + cc) * 16 + li];
        accC[cc] = f32x4{bv, bv, bv, bv};
    }
    for (int kt = 0; kt < 8; ++kt) {
        short8 a = *(const short8*)(cbuf + ((size_t)kt * 64 + lane) * 8);
        const us* wk = wfc + ((size_t)kt * 8 + wid * 2) * 512;
#pragma unroll
        for (int cc = 0; cc < 2; ++cc) {
            short8 w = *(const short8*)(wk + ((size_t)cc * 64 + lane) * 8);
            accC[cc] = __builtin_amdgcn_mfma_f32_16x16x32_bf16(a, w, accC[cc], 0, 0, 0);
        }
    }
#pragma unroll
    for (int cc = 0; cc < 2; ++cc) {
        int o = (wid * 2 + cc) * 16 + li;
#pragma unroll
        for (int r = 0; r < 4; ++r) {
            int gg = g0 + h * 4 + r;
            outp[(size_t)49152 + (size_t)gg * 192 + o] = fmaxf(accC[cc][r], 0.f);
        }
    }

    {   // relu(points) tail
        int r = t >> 4, q = t & 15;
        float4 v = ((const float4*)(pts + ((size_t)(g0 + r) << 6)))[q];
        v.x = fmaxf(v.x, 0.0f);
        v.y = fmaxf(v.y, 0.0f);
        v.z = fmaxf(v.z, 0.0f);
        v.w = fmaxf(v.w, 0.0f);
        *(float4*)(outp + 49152 + (size_t)(g0 + r) * 192 + 128 + q * 4) = v;
    }
}

extern "C" void kernel_launch(void* const* d_in, const int* in_sizes, int n_in,
                              void* d_out, int out_size, void* d_ws, size_t ws_size,
                              hipStream_t stream) {
    const float* xyz = (const float*)d_in[0];
    const float* pts = (const float*)d_in[1];
    const float* w1a = (const float*)d_in[2];
    const float* b1a = (const float*)d_in[3];
    const float* w1b = (const float*)d_in[4];
    const float* b1b = (const float*)d_in[5];
    const float* w1c = (const float*)d_in[6];
    const float* b1c = (const float*)d_in[7];
    const float* w2a = (const float*)d_in[8];
    const float* b2a = (const float*)d_in[9];
    const float* w2b = (const float*)d_in[10];
    const float* b2b = (const float*)d_in[11];
    const float* w2c = (const float*)d_in[12];
    const float* b2c = (const float*)d_in[13];
    float* outp = (float*)d_out;

    char* ws = (char*)d_ws;
    u64* keys = (u64*)ws;                            // 1 MB (written by k_s1 only)
    const u32* keys32 = (const u32*)ws;
    us* wf1a = (us*)(ws + 1048576);                  // 40 KB  (KT=5)
    us* wf1b = (us*)(ws + 1089536);                  // 64 KB  (KT=8)
    us* wf1c = (us*)(ws + 1155072);                  // 64 KB
    us* wf2a = (us*)(ws + 1220608);                  // 72 KB  (KT=9)
    us* wf2b = (us*)(ws + 1294336);                  // 64 KB
    us* wf2c = (us*)(ws + 1359872);                  // 64 KB
    us* ptsbf = (us*)(ws + 2097152);                 // 16384 x 80 us = 2.62 MB
    us* newbf = (us*)(ws + 5242880);                 // 16384 x 144 us = 4.72 MB

    k_prep<<<268, 256, 0, stream>>>(xyz, pts, w1a, wf1a, w1b, wf1b, w1c, wf1c,
                                    w2a, wf2a, w2b, wf2b, w2c, wf2c,
                                    ptsbf, newbf, outp);
    k_s1<<<1024, 256, 0, stream>>>(xyz, ptsbf, keys,
                                   wf1a, b1a, wf1b, b1b, wf1c, b1c, newbf);
    k_s2<<<1024, 256, 0, stream>>>(pts, newbf, keys32,
                                   wf2a, b2a, wf2b, b2b, wf2c, b2c, outp);
}